// Round 2
// baseline (851.294 us; speedup 1.0000x reference)
//
#include <hip/hip_runtime.h>
#include <math.h>

#define Bn 16
#define Tn 2048
#define Fn 1025
#define F4 257      // ceil(1025/4)
#define FPAD 1028
#define Dn 64
#define TB 8
#define EPSF 1e-6f

__device__ inline float waveReduceSum(float v) {
#pragma unroll
  for (int off = 32; off > 0; off >>= 1) v += __shfl_xor(v, off, 64);
  return v;
}

// ---------------- prep: basis in [f/4][d][4] layout + spacing outputs ----------------
__global__ __launch_bounds__(256) void prep_kernel(
    const float* __restrict__ freq, const float* __restrict__ spacing,
    float* __restrict__ basis4, float* __restrict__ out2, float* __restrict__ out3) {
  __shared__ float wsum[4];
  const int d = blockIdx.x;
  const int tid = threadIdx.x;
  const float sp = fmaxf(spacing[d], 1e-6f);

  float pv[5];
  float lsum = 0.f;
  int j = 0;
  for (int f = tid; f < FPAD; f += 256, ++j) {
    float p = 0.f;
    if (f < Fn) {
      float fr = freq[f];
      double arg = 6.2831853071795864769 * (double)(fr / sp);
      p = 0.5f * (1.0f + (float)cos(arg));
      lsum += p;
    }
    pv[j] = p;
  }
  float s = waveReduceSum(lsum);
  if ((tid & 63) == 0) wsum[tid >> 6] = s;
  __syncthreads();
  float total = wsum[0] + wsum[1] + wsum[2] + wsum[3];
  float mean = total * (1.0f / 1025.0f);
  float inv = 1.0f / fmaxf(mean, EPSF);

  j = 0;
  for (int f = tid; f < FPAD; f += 256, ++j) {
    basis4[((size_t)(f >> 2) * Dn + d) * 4 + (f & 3)] = pv[j] * inv;
  }
  if (tid == 0) {
    out2[d] = spacing[d];
    out3[d] = 17150.0f / sp;
  }
}

// ---------------- main fused kernel ----------------
__global__ __launch_bounds__(256, 4) void main_kernel(
    const float* __restrict__ phase, const float* __restrict__ comb,
    const float* __restrict__ scalar, const float* __restrict__ obs_m,
    const float* __restrict__ rel_m, const float* __restrict__ stpacc,
    const float* __restrict__ basis4,
    float* __restrict__ out0, float* __restrict__ out1) {
  __shared__ float u_lds[TB][FPAD];   // 32896 B -> 4 blocks/CU

  const int tid = threadIdx.x;
  const int lane = tid & 63;
  const int w = tid >> 6;
  const int blk = blockIdx.x;
  const int b = blk / (Tn / TB);
  const int t0 = (blk % (Tn / TB)) * TB;

  float rowScale[2];

  // ---- Phase 1: trough rows into LDS (wave w owns rows 2w, 2w+1), float4 loads ----
#pragma unroll
  for (int k = 0; k < 2; ++k) {
    const int r = 2 * w + k;
    const int t = t0 + r;
    const size_t bt = (size_t)b * Tn + t;
    const int a = t & 3;   // shared alignment phase for phase row and both comb rows
    const float* prow  = phase + bt * Fn - a;
    const float* c0row = comb + ((size_t)(b * 2 + 0) * Tn + t) * Fn - a;
    const float* c1row = comb + ((size_t)(b * 2 + 1) * Tn + t) * Fn - a;

    float4 pv[5], c0v[5], c1v[5];
#pragma unroll
    for (int it = 0; it < 5; ++it) {
      int i4 = lane + 64 * it;
      int i4c = i4 > 256 ? 256 : i4;
      pv[it]  = *(const float4*)(prow  + 4 * i4c);
      c0v[it] = *(const float4*)(c0row + 4 * i4c);
      c1v[it] = *(const float4*)(c1row + 4 * i4c);
    }
    // masked mean of log_mag
    float s = 0.f;
#pragma unroll
    for (int it = 0; it < 5; ++it) {
      int fbase = 4 * (lane + 64 * it) - a;
      float* pf = (float*)&pv[it];
#pragma unroll
      for (int c2 = 0; c2 < 4; ++c2) {
        bool valid = (unsigned)(fbase + c2) < 1025u;
        pf[c2] = valid ? pf[c2] : 0.f;
        s += pf[c2];
      }
    }
    s = waveReduceSum(s);
    const float mean_lm = s * (1.0f / 1025.0f);

    float su = 0.f;
#pragma unroll
    for (int it = 0; it < 5; ++it) {
      int fbase = 4 * (lane + 64 * it) - a;
      const float* pf = (const float*)&pv[it];
      const float* q0 = (const float*)&c0v[it];
      const float* q1 = (const float*)&c1v[it];
#pragma unroll
      for (int c2 = 0; c2 < 4; ++c2) {
        int f = fbase + c2;
        bool valid = (unsigned)f < 1025u;
        float tr = fmaxf(mean_lm - pf[c2], 0.f);
        float d1 = fabsf(q1[c2]) + 0.25f * fabsf(q0[c2]);
        float u = tr * (1.f + d1);
        u = valid ? u : 0.f;
        su += u;
        u_lds[r][valid ? f : 1025] = u;   // invalid comps dump 0 into pad slot 1025
      }
    }
    if (lane < 2) u_lds[r][1026 + lane] = 0.f;  // remaining pad slots
    su = waveReduceSum(su);
    rowScale[k] = 1.0f / fmaxf(su * (1.0f / 1025.0f), EPSF);
  }
  __syncthreads();

  // ---- Phase 2: f-split across waves; lane = d; segmented accumulation ----
  const float4* bq = (const float4*)basis4;
  float acc0[TB], acc1[TB], acc2[TB];
#pragma unroll
  for (int r = 0; r < TB; ++r) { acc0[r] = acc1[r] = acc2[r] = 0.f; }

  auto run = [&](int cb, int ce, float* acc) {
    for (int c = cb; c < ce; ++c) {
      float4 bv = bq[(size_t)c * Dn + lane];
      float4 uv[TB];
#pragma unroll
      for (int r = 0; r < TB; ++r) uv[r] = *(const float4*)&u_lds[r][4 * c];
#pragma unroll
      for (int r = 0; r < TB; ++r)
        acc[r] += uv[r].x * bv.x + uv[r].y * bv.y + uv[r].z * bv.z + uv[r].w * bv.w;
    }
  };
  auto runSplit = [&](int c, float* aXY, float* aZW) {
    float4 bv = bq[(size_t)c * Dn + lane];
#pragma unroll
    for (int r = 0; r < TB; ++r) {
      float4 uv = *(const float4*)&u_lds[r][4 * c];
      aXY[r] += uv.x * bv.x + uv.y * bv.y;
      aZW[r] += uv.z * bv.z + uv.w * bv.w;
    }
  };

  if (w == 0) {
    run(0, 5, acc0);           // f 0..19            band0
    runSplit(5, acc0, acc1);   // f 20,21 b0 | 22,23 b1
    run(6, 21, acc1);          // f 24..83           band1
    runSplit(21, acc1, acc2);  // f 84,85 b1 | 86,87 b2
    run(22, 64, acc2);         // f 88..255          band2
  } else if (w == 1) {
    run(64, 85, acc0);         // f 256..339         band2
    runSplit(85, acc0, acc1);  // f 340,341 b2 | 342,343 b3
    run(86, 128, acc1);        // f 344..511         band3
  } else if (w == 2) {
    run(128, 192, acc0);       // f 512..767         band3
  } else {
    run(192, 257, acc0);       // f 768..1024 (+pad) band3
  }
  __syncthreads();

  // ---- Combine band partials in reused LDS: sc[band][row][64] ----
  float* sc = &u_lds[0][0];
#pragma unroll
  for (int i = 0; i < 8; ++i) sc[tid * 8 + i] = 0.f;   // zero 2048 floats
  __syncthreads();
  if (w == 0) {
#pragma unroll
    for (int r = 0; r < TB; ++r) {
      atomicAdd(&sc[(0 * TB + r) * 64 + lane], acc0[r]);
      atomicAdd(&sc[(1 * TB + r) * 64 + lane], acc1[r]);
      atomicAdd(&sc[(2 * TB + r) * 64 + lane], acc2[r]);
    }
  } else if (w == 1) {
#pragma unroll
    for (int r = 0; r < TB; ++r) {
      atomicAdd(&sc[(2 * TB + r) * 64 + lane], acc0[r]);
      atomicAdd(&sc[(3 * TB + r) * 64 + lane], acc1[r]);
    }
  } else {
#pragma unroll
    for (int r = 0; r < TB; ++r) {
      atomicAdd(&sc[(3 * TB + r) * 64 + lane], acc0[r]);
    }
  }
  __syncthreads();

  // ---- Phase 3: channels + writes (wave w owns rows 2w, 2w+1) ----
  const float invD0 = 1.0f / 22.0f, invD1 = 1.0f / 64.0f,
              invD2 = 1.0f / 256.0f, invD3 = 1.0f / 683.0f;
#pragma unroll
  for (int k = 0; k < 2; ++k) {
    const int r = 2 * w + k;
    const int t = t0 + r;
    const size_t bt = (size_t)b * Tn + t;

    float b0 = sc[(0 * TB + r) * 64 + lane];
    float b1 = sc[(1 * TB + r) * 64 + lane];
    float b2 = sc[(2 * TB + r) * 64 + lane];
    float b3 = sc[(3 * TB + r) * 64 + lane];
    float tot = b0 + b1 + b2 + b3;

    float sv = fmaxf(stpacc[bt * Dn + lane], 0.f);
    float ssum = waveReduceSum(sv);
    float stp = sv / fmaxf(ssum * (1.0f / 64.0f), EPSF);

    float4 scv = *(const float4*)(scalar + bt * 4);
    float4 om  = *(const float4*)(obs_m  + bt * 4);
    float4 rm  = *(const float4*)(rel_m  + bt * 4);
    float obs_q = (om.x + om.y + om.z + om.w) * 0.25f;
    float rel_q = (rm.x + rm.y + rm.z + rm.w) * 0.25f;
    float is_snd = fminf(fmaxf(scv.x, 0.f), 1.f);
    float rho = fabsf(fminf(fmaxf(scv.y, -1.f), 1.f));

    float rs = rowScale[k];
    float c0 = tot * rs * (1.0f / 1025.0f);
    float c1 = b0 * rs * invD0;
    float c2 = b1 * rs * invD1;
    float c3 = b2 * rs * invD2;
    float c4 = b3 * rs * invD3;

    float mean10 = (c0 + c1 + c2 + c3 + c4 + stp + obs_q + rel_q + is_snd + rho) * 0.1f;
    float logit = mean10 * (0.5f + 0.5f * is_snd);

    float2* op = (float2*)(out0 + (bt * Dn + lane) * 10);
    op[0] = make_float2(c0, c1);
    op[1] = make_float2(c2, c3);
    op[2] = make_float2(c4, stp);
    op[3] = make_float2(obs_q, rel_q);
    op[4] = make_float2(is_snd, rho);
    out1[bt * Dn + lane] = logit;
  }
}

extern "C" void kernel_launch(void* const* d_in, const int* in_sizes, int n_in,
                              void* d_out, int out_size, void* d_ws, size_t ws_size,
                              hipStream_t stream) {
  const float* phase   = (const float*)d_in[0];
  const float* comb    = (const float*)d_in[1];
  const float* scalar  = (const float*)d_in[2];
  const float* obs_m   = (const float*)d_in[3];
  const float* rel_m   = (const float*)d_in[4];
  const float* stpacc  = (const float*)d_in[5];
  const float* freq    = (const float*)d_in[6];
  const float* spacing = (const float*)d_in[7];

  float* out  = (float*)d_out;
  float* out0 = out;                                    // (B,T,D,10)
  float* out1 = out + (size_t)Bn * Tn * Dn * 10;        // (B,T,D)
  float* out2 = out1 + (size_t)Bn * Tn * Dn;            // (D,)
  float* out3 = out2 + Dn;                              // (D,)

  float* basis4 = (float*)d_ws;                         // F4*64*4 floats

  prep_kernel<<<Dn, 256, 0, stream>>>(freq, spacing, basis4, out2, out3);
  main_kernel<<<Bn * Tn / TB, 256, 0, stream>>>(
      phase, comb, scalar, obs_m, rel_m, stpacc, basis4, out0, out1);
}

// Round 3
// 433.974 us; speedup vs baseline: 1.9616x; 1.9616x over previous
//
#include <hip/hip_runtime.h>
#include <math.h>

#define Bn 16
#define Tn 2048
#define Fn 1025
#define F4 257        // ceil(1025/4)
#define USTRIDE 1028  // u row stride in floats (16B aligned, 3 pad slots)
#define Dn 64
#define EPSF 1e-6f

__device__ inline float waveReduceSum(float v) {
#pragma unroll
  for (int off = 32; off > 0; off >>= 1) v += __shfl_xor(v, off, 64);
  return v;
}

// ---------------- prep: basis in [f/4][d][4] layout + spacing outputs ----------------
__global__ __launch_bounds__(256) void prep_kernel(
    const float* __restrict__ freq, const float* __restrict__ spacing,
    float* __restrict__ basis4, float* __restrict__ out2, float* __restrict__ out3) {
  __shared__ float wsum[4];
  const int d = blockIdx.x;
  const int tid = threadIdx.x;
  const float sp = fmaxf(spacing[d], 1e-6f);

  float pv[5];
  float lsum = 0.f;
  int j = 0;
  for (int f = tid; f < 4 * F4; f += 256, ++j) {
    float p = 0.f;
    if (f < Fn) {
      float fr = freq[f];
      double arg = 6.2831853071795864769 * (double)(fr / sp);
      p = 0.5f * (1.0f + (float)cos(arg));
      lsum += p;
    }
    pv[j] = p;
  }
  float s = waveReduceSum(lsum);
  if ((tid & 63) == 0) wsum[tid >> 6] = s;
  __syncthreads();
  float total = wsum[0] + wsum[1] + wsum[2] + wsum[3];
  float inv = 1.0f / fmaxf(total * (1.0f / 1025.0f), EPSF);

  j = 0;
  for (int f = tid; f < 4 * F4; f += 256, ++j) {
    basis4[((size_t)(f >> 2) * Dn + d) * 4 + (f & 3)] = pv[j] * inv;
  }
  if (tid == 0) {
    out2[d] = spacing[d];
    out3[d] = 17150.0f / sp;
  }
}

// ---------------- K1: trough rows (normalized, scaled) -> u_ws ----------------
__global__ __launch_bounds__(256) void trough_kernel(
    const float* __restrict__ phase, const float* __restrict__ comb,
    float* __restrict__ u_ws) {
  const int lane = threadIdx.x & 63;
  const int w = threadIdx.x >> 6;
  const int row = blockIdx.x * 4 + w;   // == b*Tn + t
  const int b = row >> 11;
  const int t = row & 2047;

  const float* prow  = phase + (size_t)row * Fn;
  const float* c0row = comb + ((size_t)(b * 2 + 0) * Tn + t) * Fn;
  const float* c1row = comb + ((size_t)(b * 2 + 1) * Tn + t) * Fn;

  float4 pv[5], c0v[5], c1v[5];
#pragma unroll
  for (int it = 0; it < 5; ++it) {
    const int i = lane + 64 * it;
    if (i < 256) {
      pv[it]  = *(const float4*)(prow  + 4 * i);
      c0v[it] = *(const float4*)(c0row + 4 * i);
      c1v[it] = *(const float4*)(c1row + 4 * i);
    } else if (i == 256) {
      pv[it]  = make_float4(prow[1024],  0.f, 0.f, 0.f);
      c0v[it] = make_float4(c0row[1024], 0.f, 0.f, 0.f);
      c1v[it] = make_float4(c1row[1024], 0.f, 0.f, 0.f);
    } else {
      pv[it]  = make_float4(0.f, 0.f, 0.f, 0.f);
      c0v[it] = make_float4(0.f, 0.f, 0.f, 0.f);
      c1v[it] = make_float4(0.f, 0.f, 0.f, 0.f);
    }
  }

  // mean(log_mag): invalid slots are already zero
  float s = 0.f;
#pragma unroll
  for (int it = 0; it < 5; ++it)
    s += pv[it].x + pv[it].y + pv[it].z + pv[it].w;
  s = waveReduceSum(s);
  const float mean_lm = s * (1.0f / 1025.0f);

  // u = relu(mean - lm) * (1 + |c1| + 0.25|c0|), masked
  float4 uv[5];
  float su = 0.f;
#pragma unroll
  for (int it = 0; it < 5; ++it) {
    const int i = lane + 64 * it;
    float4 u;
    const float* pf = (const float*)&pv[it];
    const float* q0 = (const float*)&c0v[it];
    const float* q1 = (const float*)&c1v[it];
    float* uf = (float*)&u;
#pragma unroll
    for (int c2 = 0; c2 < 4; ++c2) {
      float tr = fmaxf(mean_lm - pf[c2], 0.f);
      float d1 = fabsf(q1[c2]) + 0.25f * fabsf(q0[c2]);
      uf[c2] = tr * (1.f + d1);
    }
    if (i > 256) { u.x = 0.f; u.y = 0.f; u.z = 0.f; u.w = 0.f; }
    else if (i == 256) { u.y = 0.f; u.z = 0.f; u.w = 0.f; }
    uv[it] = u;
    su += u.x + u.y + u.z + u.w;
  }
  su = waveReduceSum(su);
  const float rs = 1.0f / fmaxf(su * (1.0f / 1025.0f), EPSF);

  float* urow = u_ws + (size_t)row * USTRIDE;
#pragma unroll
  for (int it = 0; it < 5; ++it) {
    const int i = lane + 64 * it;
    if (i <= 256) {
      float4 u = uv[it];
      u.x *= rs; u.y *= rs; u.z *= rs; u.w *= rs;
      *(float4*)(urow + 4 * i) = u;
    }
  }
}

// ---------------- K2: segmented dot products + channels + writes ----------------
__global__ __launch_bounds__(256) void score_kernel(
    const float* __restrict__ u_ws, const float* __restrict__ basis4,
    const float* __restrict__ scalar, const float* __restrict__ obs_m,
    const float* __restrict__ rel_m, const float* __restrict__ stpacc,
    float* __restrict__ out0, float* __restrict__ out1) {
  const int lane = threadIdx.x & 63;
  int w = threadIdx.x >> 6;
  w = __builtin_amdgcn_readfirstlane(w);        // force wave-uniform
  const int wg = blockIdx.x * 4 + w;            // 0..4095
  const int row0 = wg * 8;
  const float* ur = u_ws + (size_t)row0 * USTRIDE;
  const float4* bq = (const float4*)basis4;

  float a0[8], a1[8], a2[8], a3[8];
#pragma unroll
  for (int r = 0; r < 8; ++r) { a0[r] = 0.f; a1[r] = 0.f; a2[r] = 0.f; a3[r] = 0.f; }

  auto run = [&](int cb, int ce, float* acc) {
    for (int c = cb; c < ce; ++c) {
      float4 bv = bq[(size_t)c * Dn + lane];
#pragma unroll
      for (int r = 0; r < 8; ++r) {
        float4 uvr = *(const float4*)(ur + (size_t)r * USTRIDE + 4 * c);
        acc[r] += uvr.x * bv.x + uvr.y * bv.y + uvr.z * bv.z + uvr.w * bv.w;
      }
    }
  };
  auto runSplit = [&](int c, float* aA, float* aB) {
    float4 bv = bq[(size_t)c * Dn + lane];
#pragma unroll
    for (int r = 0; r < 8; ++r) {
      float4 uvr = *(const float4*)(ur + (size_t)r * USTRIDE + 4 * c);
      aA[r] += uvr.x * bv.x + uvr.y * bv.y;
      aB[r] += uvr.z * bv.z + uvr.w * bv.w;
    }
  };

  run(0, 5, a0);            // f 0..19             band0
  runSplit(5, a0, a1);      // f 20,21 b0 | 22,23 b1
  run(6, 21, a1);           // f 24..83            band1
  runSplit(21, a1, a2);     // f 84,85 b1 | 86,87 b2
  run(22, 85, a2);          // f 88..339           band2
  runSplit(85, a2, a3);     // f 340,341 b2 | 342,343 b3
  run(86, F4, a3);          // f 344..1024 (+pad)  band3

  // channels + writes (rs already folded into u in K1)
#pragma unroll
  for (int r = 0; r < 8; ++r) {
    const size_t bt = (size_t)(row0 + r);       // == b*Tn + t

    float b0 = a0[r], b1 = a1[r], b2 = a2[r], b3 = a3[r];
    float tot = b0 + b1 + b2 + b3;

    float sv = fmaxf(stpacc[bt * Dn + lane], 0.f);
    float ssum = waveReduceSum(sv);
    float stp = sv / fmaxf(ssum * (1.0f / 64.0f), EPSF);

    float4 scv = *(const float4*)(scalar + bt * 4);
    float4 om  = *(const float4*)(obs_m  + bt * 4);
    float4 rm  = *(const float4*)(rel_m  + bt * 4);
    float obs_q = (om.x + om.y + om.z + om.w) * 0.25f;
    float rel_q = (rm.x + rm.y + rm.z + rm.w) * 0.25f;
    float is_snd = fminf(fmaxf(scv.x, 0.f), 1.f);
    float rho = fabsf(fminf(fmaxf(scv.y, -1.f), 1.f));

    float c0 = tot * (1.0f / 1025.0f);
    float c1 = b0 * (1.0f / 22.0f);
    float c2 = b1 * (1.0f / 64.0f);
    float c3 = b2 * (1.0f / 256.0f);
    float c4 = b3 * (1.0f / 683.0f);

    float mean10 = (c0 + c1 + c2 + c3 + c4 + stp + obs_q + rel_q + is_snd + rho) * 0.1f;
    float logit = mean10 * (0.5f + 0.5f * is_snd);

    float2* op = (float2*)(out0 + (bt * Dn + lane) * 10);
    op[0] = make_float2(c0, c1);
    op[1] = make_float2(c2, c3);
    op[2] = make_float2(c4, stp);
    op[3] = make_float2(obs_q, rel_q);
    op[4] = make_float2(is_snd, rho);
    out1[bt * Dn + lane] = logit;
  }
}

extern "C" void kernel_launch(void* const* d_in, const int* in_sizes, int n_in,
                              void* d_out, int out_size, void* d_ws, size_t ws_size,
                              hipStream_t stream) {
  const float* phase   = (const float*)d_in[0];
  const float* comb    = (const float*)d_in[1];
  const float* scalar  = (const float*)d_in[2];
  const float* obs_m   = (const float*)d_in[3];
  const float* rel_m   = (const float*)d_in[4];
  const float* stpacc  = (const float*)d_in[5];
  const float* freq    = (const float*)d_in[6];
  const float* spacing = (const float*)d_in[7];

  float* out  = (float*)d_out;
  float* out0 = out;                                    // (B,T,D,10)
  float* out1 = out + (size_t)Bn * Tn * Dn * 10;        // (B,T,D)
  float* out2 = out1 + (size_t)Bn * Tn * Dn;            // (D,)
  float* out3 = out2 + Dn;                              // (D,)

  float* basis4 = (float*)d_ws;                         // 65792 floats
  float* u_ws   = basis4 + 65792;                       // 32768*1028 floats (~134.7 MB)

  const int rows = Bn * Tn;                             // 32768

  prep_kernel<<<Dn, 256, 0, stream>>>(freq, spacing, basis4, out2, out3);
  trough_kernel<<<rows / 4, 256, 0, stream>>>(phase, comb, u_ws);
  score_kernel<<<rows / 8 / 4, 256, 0, stream>>>(
      u_ws, basis4, scalar, obs_m, rel_m, stpacc, out0, out1);
}

// Round 4
// 173.476 us; speedup vs baseline: 4.9073x; 2.5016x over previous
//
#include <hip/hip_runtime.h>
#include <hip/hip_fp16.h>
#include <math.h>

#define Bn 16
#define Tn 2048
#define Fn 1025
#define KP 1056       // padded K = 33 * 32
#define Dn 64
#define EPSF 1e-6f

typedef __attribute__((ext_vector_type(8))) _Float16 f16x8;
typedef __attribute__((ext_vector_type(4))) _Float16 f16x4;
typedef __attribute__((ext_vector_type(4))) float f32x4;

__device__ inline float waveReduceSum(float v) {
#pragma unroll
  for (int off = 32; off > 0; off >>= 1) v += __shfl_xor(v, off, 64);
  return v;
}

// ---------------- prep: basisT[d][k] fp16 (normalized), spacing outputs ----------------
__global__ __launch_bounds__(256) void prep_kernel(
    const float* __restrict__ freq, const float* __restrict__ spacing,
    _Float16* __restrict__ basisT, float* __restrict__ out2, float* __restrict__ out3) {
  __shared__ float wsum[4];
  const int d = blockIdx.x;
  const int tid = threadIdx.x;
  const float sp = fmaxf(spacing[d], 1e-6f);

  float pv[5];
  float lsum = 0.f;
#pragma unroll
  for (int it = 0; it < 5; ++it) {
    int f = tid + 256 * it;
    float p = 0.f;
    if (f < Fn) {
      double arg = 6.2831853071795864769 * (double)(freq[f] / sp);
      p = 0.5f * (1.0f + (float)cos(arg));
      lsum += p;
    }
    pv[it] = p;
  }
  float s = waveReduceSum(lsum);
  if ((tid & 63) == 0) wsum[tid >> 6] = s;
  __syncthreads();
  float inv = 1.0f / fmaxf((wsum[0] + wsum[1] + wsum[2] + wsum[3]) * (1.0f / 1025.0f), EPSF);

#pragma unroll
  for (int it = 0; it < 5; ++it) {
    int f = tid + 256 * it;
    if (f < KP) basisT[(size_t)d * KP + f] = (_Float16)(pv[it] * inv);
  }
  if (tid == 0) {
    out2[d] = spacing[d];
    out3[d] = 17150.0f / sp;
  }
}

// ---------------- K1: trough rows (normalized, scaled) -> u16 fp16 plane ----------------
__global__ __launch_bounds__(256) void trough_kernel(
    const float* __restrict__ phase, const float* __restrict__ comb,
    _Float16* __restrict__ u16) {
  const int lane = threadIdx.x & 63;
  const int w = threadIdx.x >> 6;
  const int row = blockIdx.x * 4 + w;   // == b*Tn + t
  const int b = row >> 11;
  const int t = row & 2047;

  const float* prow  = phase + (size_t)row * Fn;
  const float* c0row = comb + ((size_t)(b * 2 + 0) * Tn + t) * Fn;
  const float* c1row = comb + ((size_t)(b * 2 + 1) * Tn + t) * Fn;

  float4 pv[5], c0v[5], c1v[5];
#pragma unroll
  for (int it = 0; it < 5; ++it) {
    const int i = lane + 64 * it;
    if (i < 256) {
      pv[it]  = *(const float4*)(prow  + 4 * i);
      c0v[it] = *(const float4*)(c0row + 4 * i);
      c1v[it] = *(const float4*)(c1row + 4 * i);
    } else if (i == 256) {
      pv[it]  = make_float4(prow[1024],  0.f, 0.f, 0.f);
      c0v[it] = make_float4(c0row[1024], 0.f, 0.f, 0.f);
      c1v[it] = make_float4(c1row[1024], 0.f, 0.f, 0.f);
    } else {
      pv[it]  = make_float4(0.f, 0.f, 0.f, 0.f);
      c0v[it] = make_float4(0.f, 0.f, 0.f, 0.f);
      c1v[it] = make_float4(0.f, 0.f, 0.f, 0.f);
    }
  }

  float s = 0.f;
#pragma unroll
  for (int it = 0; it < 5; ++it)
    s += pv[it].x + pv[it].y + pv[it].z + pv[it].w;
  s = waveReduceSum(s);
  const float mean_lm = s * (1.0f / 1025.0f);

  float4 uv[5];
  float su = 0.f;
#pragma unroll
  for (int it = 0; it < 5; ++it) {
    const int i = lane + 64 * it;
    float4 u;
    const float* pf = (const float*)&pv[it];
    const float* q0 = (const float*)&c0v[it];
    const float* q1 = (const float*)&c1v[it];
    float* uf = (float*)&u;
#pragma unroll
    for (int c2 = 0; c2 < 4; ++c2) {
      float tr = fmaxf(mean_lm - pf[c2], 0.f);
      float d1 = fabsf(q1[c2]) + 0.25f * fabsf(q0[c2]);
      uf[c2] = tr * (1.f + d1);
    }
    if (i > 256) { u.x = 0.f; u.y = 0.f; u.z = 0.f; u.w = 0.f; }
    else if (i == 256) { u.y = 0.f; u.z = 0.f; u.w = 0.f; }
    uv[it] = u;
    su += u.x + u.y + u.z + u.w;
  }
  su = waveReduceSum(su);
  const float rs = 1.0f / fmaxf(su * (1.0f / 1025.0f), EPSF);

  _Float16* urow = u16 + (size_t)row * KP;
#pragma unroll
  for (int it = 0; it < 5; ++it) {
    const int i = lane + 64 * it;
    if (i < 264) {                       // k < 1056 (quads 257..263 write zeros)
      const float* uf = (const float*)&uv[it];
      f16x4 hv;
#pragma unroll
      for (int c2 = 0; c2 < 4; ++c2) hv[c2] = (_Float16)(uf[c2] * rs);
      *(f16x4*)(urow + 4 * i) = hv;
    }
  }
}

// ---------------- K2: MFMA GEMM, cumulative band snapshots -> cum[bt][4][64] ----------------
__global__ __launch_bounds__(256) void gemm_kernel(
    const _Float16* __restrict__ u16, const _Float16* __restrict__ basisT,
    float* __restrict__ cum) {
  const int lane = threadIdx.x & 63;
  const int w = __builtin_amdgcn_readfirstlane(threadIdx.x >> 6);
  const int wid = blockIdx.x * 4 + w;   // 0..4095
  const int mt = wid >> 1;              // 16-row M-tile index
  const int nh = wid & 1;               // N half (d 0..31 or 32..63)
  const int row0 = mt * 16;
  const int m16 = lane & 15;
  const int kg = lane >> 4;

  const _Float16* Ap = u16 + (size_t)(row0 + m16) * KP + kg * 8;
  const int d0 = nh * 32 + m16;
  const _Float16* B0 = basisT + (size_t)d0 * KP + kg * 8;
  const _Float16* B1 = basisT + (size_t)(d0 + 16) * KP + kg * 8;

  f32x4 acc0 = {0.f, 0.f, 0.f, 0.f};
  f32x4 acc1 = {0.f, 0.f, 0.f, 0.f};

  auto loadA = [&](int kt) { return *(const f16x8*)(Ap + kt * 32); };
  auto tileA = [&](int kt, f16x8 a) {
    f16x8 b0 = *(const f16x8*)(B0 + kt * 32);
    f16x8 b1 = *(const f16x8*)(B1 + kt * 32);
    acc0 = __builtin_amdgcn_mfma_f32_16x16x32_f16(a, b0, acc0, 0, 0, 0);
    acc1 = __builtin_amdgcn_mfma_f32_16x16x32_f16(a, b1, acc1, 0, 0, 0);
  };
  auto storeCum = [&](int bnd) {
#pragma unroll
    for (int r = 0; r < 4; ++r) {
      size_t base = ((size_t)(row0 + kg * 4 + r) * 4 + bnd) * 64;
      cum[base + d0]      = acc0[r];
      cum[base + d0 + 16] = acc1[r];
    }
  };
  auto boundary = [&](int kt, int KB, int bnd) {
    f16x8 a = loadA(kt);
    const int kb = kt * 32 + kg * 8;
    f16x8 alo, ahi;
#pragma unroll
    for (int j = 0; j < 8; ++j) {
      bool lo = (kb + j) < KB;
      alo[j] = lo ? a[j] : (_Float16)0.f;
      ahi[j] = lo ? (_Float16)0.f : a[j];
    }
    tileA(kt, alo);
    storeCum(bnd);
    tileA(kt, ahi);
  };

  boundary(0, 22, 0);                    // band0 ends at k=22
  tileA(1, loadA(1));
  boundary(2, 86, 1);                    // band1 ends at k=86
#pragma unroll 4
  for (int kt = 3; kt < 10; ++kt) tileA(kt, loadA(kt));
  boundary(10, 342, 2);                  // band2 ends at k=342
#pragma unroll 4
  for (int kt = 11; kt < 33; ++kt) tileA(kt, loadA(kt));
  storeCum(3);                           // full sum
}

// ---------------- K3: epilogue — band diffs + scalar channels + writes ----------------
__global__ __launch_bounds__(256) void epi_kernel(
    const float* __restrict__ cum,
    const float* __restrict__ scalar, const float* __restrict__ obs_m,
    const float* __restrict__ rel_m, const float* __restrict__ stpacc,
    float* __restrict__ out0, float* __restrict__ out1) {
  const int lane = threadIdx.x & 63;
  const int w = __builtin_amdgcn_readfirstlane(threadIdx.x >> 6);
  const int row0 = (blockIdx.x * 4 + w) * 8;

#pragma unroll
  for (int r = 0; r < 8; ++r) {
    const size_t bt = (size_t)(row0 + r);

    float q0 = cum[(bt * 4 + 0) * 64 + lane];
    float q1 = cum[(bt * 4 + 1) * 64 + lane];
    float q2 = cum[(bt * 4 + 2) * 64 + lane];
    float q3 = cum[(bt * 4 + 3) * 64 + lane];
    float b0 = q0, b1 = q1 - q0, b2 = q2 - q1, b3 = q3 - q2;
    float tot = q3;

    float sv = fmaxf(stpacc[bt * Dn + lane], 0.f);
    float ssum = waveReduceSum(sv);
    float stp = sv / fmaxf(ssum * (1.0f / 64.0f), EPSF);

    float4 scv = *(const float4*)(scalar + bt * 4);
    float4 om  = *(const float4*)(obs_m  + bt * 4);
    float4 rm  = *(const float4*)(rel_m  + bt * 4);
    float obs_q = (om.x + om.y + om.z + om.w) * 0.25f;
    float rel_q = (rm.x + rm.y + rm.z + rm.w) * 0.25f;
    float is_snd = fminf(fmaxf(scv.x, 0.f), 1.f);
    float rho = fabsf(fminf(fmaxf(scv.y, -1.f), 1.f));

    float c0 = tot * (1.0f / 1025.0f);
    float c1 = b0 * (1.0f / 22.0f);
    float c2 = b1 * (1.0f / 64.0f);
    float c3 = b2 * (1.0f / 256.0f);
    float c4 = b3 * (1.0f / 683.0f);

    float mean10 = (c0 + c1 + c2 + c3 + c4 + stp + obs_q + rel_q + is_snd + rho) * 0.1f;
    float logit = mean10 * (0.5f + 0.5f * is_snd);

    float2* op = (float2*)(out0 + (bt * Dn + lane) * 10);
    op[0] = make_float2(c0, c1);
    op[1] = make_float2(c2, c3);
    op[2] = make_float2(c4, stp);
    op[3] = make_float2(obs_q, rel_q);
    op[4] = make_float2(is_snd, rho);
    out1[bt * Dn + lane] = logit;
  }
}

extern "C" void kernel_launch(void* const* d_in, const int* in_sizes, int n_in,
                              void* d_out, int out_size, void* d_ws, size_t ws_size,
                              hipStream_t stream) {
  const float* phase   = (const float*)d_in[0];
  const float* comb    = (const float*)d_in[1];
  const float* scalar  = (const float*)d_in[2];
  const float* obs_m   = (const float*)d_in[3];
  const float* rel_m   = (const float*)d_in[4];
  const float* stpacc  = (const float*)d_in[5];
  const float* freq    = (const float*)d_in[6];
  const float* spacing = (const float*)d_in[7];

  float* out  = (float*)d_out;
  float* out0 = out;                                    // (B,T,D,10)
  float* out1 = out + (size_t)Bn * Tn * Dn * 10;        // (B,T,D)
  float* out2 = out1 + (size_t)Bn * Tn * Dn;            // (D,)
  float* out3 = out2 + Dn;                              // (D,)

  const int rows = Bn * Tn;                             // 32768
  _Float16* u16    = (_Float16*)d_ws;                   // rows*KP fp16   = 69.2 MB
  _Float16* basisT = u16 + (size_t)rows * KP;           // 64*KP fp16     = 135 KB
  float*    cum    = (float*)(basisT + (size_t)Dn * KP);// rows*4*64 f32  = 33.5 MB

  prep_kernel<<<Dn, 256, 0, stream>>>(freq, spacing, basisT, out2, out3);
  trough_kernel<<<rows / 4, 256, 0, stream>>>(phase, comb, u16);
  gemm_kernel<<<rows / 16 * 2 / 4, 256, 0, stream>>>(u16, basisT, cum);
  epi_kernel<<<rows / 8 / 4, 256, 0, stream>>>(
      cum, scalar, obs_m, rel_m, stpacc, out0, out1);
}

// Round 5
// 124.018 us; speedup vs baseline: 6.8643x; 1.3988x over previous
//
#include <hip/hip_runtime.h>
#include <hip/hip_fp16.h>
#include <math.h>

#define Bn 16
#define Tn 2048
#define Fn 1025
#define KP 1056       // padded K = 33 * 32 (basisT row stride)
#define KROW 1064     // LDS u row stride in fp16 (2128 B -> 20 mod 32 banks/row)
#define Dn 64
#define EPSF 1e-6f

typedef __attribute__((ext_vector_type(8))) _Float16 f16x8;
typedef __attribute__((ext_vector_type(4))) _Float16 f16x4;
typedef __attribute__((ext_vector_type(4))) float f32x4;

__device__ inline float waveReduceSum(float v) {
#pragma unroll
  for (int off = 32; off > 0; off >>= 1) v += __shfl_xor(v, off, 64);
  return v;
}

// ---------------- prep: basisT[d][k] fp16 (normalized), spacing outputs ----------------
__global__ __launch_bounds__(256) void prep_kernel(
    const float* __restrict__ freq, const float* __restrict__ spacing,
    _Float16* __restrict__ basisT, float* __restrict__ out2, float* __restrict__ out3) {
  __shared__ float wsum[4];
  const int d = blockIdx.x;
  const int tid = threadIdx.x;
  const float sp = fmaxf(spacing[d], 1e-6f);

  float pv[5];
  float lsum = 0.f;
#pragma unroll
  for (int it = 0; it < 5; ++it) {
    int f = tid + 256 * it;
    float p = 0.f;
    if (f < Fn) {
      double arg = 6.2831853071795864769 * (double)(freq[f] / sp);
      p = 0.5f * (1.0f + (float)cos(arg));
      lsum += p;
    }
    pv[it] = p;
  }
  float s = waveReduceSum(lsum);
  if ((tid & 63) == 0) wsum[tid >> 6] = s;
  __syncthreads();
  float inv = 1.0f / fmaxf((wsum[0] + wsum[1] + wsum[2] + wsum[3]) * (1.0f / 1025.0f), EPSF);

#pragma unroll
  for (int it = 0; it < 5; ++it) {
    int f = tid + 256 * it;
    if (f < KP) basisT[(size_t)d * KP + f] = (_Float16)(pv[it] * inv);
  }
  if (tid == 0) {
    out2[d] = spacing[d];
    out3[d] = 17150.0f / sp;
  }
}

// ---------------- fused: trough -> LDS -> MFMA -> epilogue ----------------
__global__ __launch_bounds__(256) void fused_kernel(
    const float* __restrict__ phase, const float* __restrict__ comb,
    const _Float16* __restrict__ basisT,
    const float* __restrict__ scalar, const float* __restrict__ obs_m,
    const float* __restrict__ rel_m, const float* __restrict__ stpacc,
    float* __restrict__ out0, float* __restrict__ out1) {
  __shared__ _Float16 uLDS[16 * KROW];   // 34048 B; later reused as cum[16][5][64] f32

  const int lane = threadIdx.x & 63;
  const int w = __builtin_amdgcn_readfirstlane(threadIdx.x >> 6);
  const int row0 = blockIdx.x * 16;

  // ---- Phase 1: trough for rows 4w..4w+3, u*rs (fp16) -> LDS ----
#pragma unroll 1
  for (int k4 = 0; k4 < 4; ++k4) {
    const int rl = w * 4 + k4;
    const int row = row0 + rl;
    const int b = row >> 11;
    const int t = row & 2047;

    const float* prow  = phase + (size_t)row * Fn;
    const float* c0row = comb + ((size_t)(b * 2 + 0) * Tn + t) * Fn;
    const float* c1row = comb + ((size_t)(b * 2 + 1) * Tn + t) * Fn;

    float4 pv[5], c0v[5], c1v[5];
#pragma unroll
    for (int it = 0; it < 5; ++it) {
      const int i = lane + 64 * it;
      if (i < 256) {
        pv[it]  = *(const float4*)(prow  + 4 * i);
        c0v[it] = *(const float4*)(c0row + 4 * i);
        c1v[it] = *(const float4*)(c1row + 4 * i);
      } else if (i == 256) {
        pv[it]  = make_float4(prow[1024],  0.f, 0.f, 0.f);
        c0v[it] = make_float4(c0row[1024], 0.f, 0.f, 0.f);
        c1v[it] = make_float4(c1row[1024], 0.f, 0.f, 0.f);
      } else {
        pv[it]  = make_float4(0.f, 0.f, 0.f, 0.f);
        c0v[it] = make_float4(0.f, 0.f, 0.f, 0.f);
        c1v[it] = make_float4(0.f, 0.f, 0.f, 0.f);
      }
    }

    float s = 0.f;
#pragma unroll
    for (int it = 0; it < 5; ++it)
      s += pv[it].x + pv[it].y + pv[it].z + pv[it].w;
    s = waveReduceSum(s);
    const float mean_lm = s * (1.0f / 1025.0f);

    float4 uv[5];
    float su = 0.f;
#pragma unroll
    for (int it = 0; it < 5; ++it) {
      const int i = lane + 64 * it;
      float4 u;
      const float* pf = (const float*)&pv[it];
      const float* q0 = (const float*)&c0v[it];
      const float* q1 = (const float*)&c1v[it];
      float* uf = (float*)&u;
#pragma unroll
      for (int c2 = 0; c2 < 4; ++c2) {
        float tr = fmaxf(mean_lm - pf[c2], 0.f);
        float d1 = fabsf(q1[c2]) + 0.25f * fabsf(q0[c2]);
        uf[c2] = tr * (1.f + d1);
      }
      if (i > 256) { u.x = 0.f; u.y = 0.f; u.z = 0.f; u.w = 0.f; }
      else if (i == 256) { u.y = 0.f; u.z = 0.f; u.w = 0.f; }
      uv[it] = u;
      su += u.x + u.y + u.z + u.w;
    }
    su = waveReduceSum(su);
    const float rs = 1.0f / fmaxf(su * (1.0f / 1025.0f), EPSF);

    _Float16* urow = uLDS + (size_t)rl * KROW;
#pragma unroll
    for (int it = 0; it < 5; ++it) {
      const int i = lane + 64 * it;
      if (i < 264) {                       // k < 1056 (quads 257..263 store zeros)
        const float* uf = (const float*)&uv[it];
        f16x4 hv;
#pragma unroll
        for (int c2 = 0; c2 < 4; ++c2) hv[c2] = (_Float16)(uf[c2] * rs);
        *(f16x4*)(urow + 4 * i) = hv;
      }
    }
  }
  __syncthreads();

  // ---- Phase 2: MFMA. wave = (khalf = w>>1, nhalf = w&1) ----
  const int m16 = lane & 15;
  const int kg = lane >> 4;
  const int nh = w & 1;
  const int kh = w >> 1;
  const int d0 = nh * 32 + m16;

  const _Float16* ALp = uLDS + (size_t)m16 * KROW + kg * 8;
  const _Float16* B0 = basisT + (size_t)d0 * KP + kg * 8;
  const _Float16* B1 = basisT + (size_t)(d0 + 16) * KP + kg * 8;

  f32x4 acc0 = {0.f, 0.f, 0.f, 0.f};
  f32x4 acc1 = {0.f, 0.f, 0.f, 0.f};
  f32x4 s0a = acc0, s0b = acc0, s1a = acc0, s1b = acc0, s2a = acc0, s2b = acc0;

  auto loadA = [&](int kt) { return *(const f16x8*)(ALp + kt * 32); };
  auto tileA = [&](int kt, f16x8 a) {
    f16x8 b0 = *(const f16x8*)(B0 + kt * 32);
    f16x8 b1 = *(const f16x8*)(B1 + kt * 32);
    acc0 = __builtin_amdgcn_mfma_f32_16x16x32_f16(a, b0, acc0, 0, 0, 0);
    acc1 = __builtin_amdgcn_mfma_f32_16x16x32_f16(a, b1, acc1, 0, 0, 0);
  };
  auto boundary = [&](int kt, int KB, f32x4& sa, f32x4& sb) {
    f16x8 a = loadA(kt);
    const int kb = kt * 32 + kg * 8;
    f16x8 alo, ahi;
#pragma unroll
    for (int j = 0; j < 8; ++j) {
      bool lo = (kb + j) < KB;
      alo[j] = lo ? a[j] : (_Float16)0.f;
      ahi[j] = lo ? (_Float16)0.f : a[j];
    }
    tileA(kt, alo);
    sa = acc0; sb = acc1;
    tileA(kt, ahi);
  };

  if (kh == 0) {
    boundary(0, 22, s0a, s0b);               // band0 ends k=22
    tileA(1, loadA(1));
    boundary(2, 86, s1a, s1b);               // band1 ends k=86
#pragma unroll
    for (int kt = 3; kt < 10; ++kt) tileA(kt, loadA(kt));
    boundary(10, 342, s2a, s2b);             // band2 ends k=342
#pragma unroll
    for (int kt = 11; kt < 16; ++kt) tileA(kt, loadA(kt));
  } else {
#pragma unroll
    for (int kt = 16; kt < 33; ++kt) tileA(kt, loadA(kt));
  }
  __syncthreads();   // u reads done; reuse LDS as cum[16][5][64] f32

  float* cumL = (float*)uLDS;
  auto stor = [&](int slot, const f32x4& v0, const f32x4& v1) {
#pragma unroll
    for (int r = 0; r < 4; ++r) {
      const int rr = kg * 4 + r;
      cumL[(rr * 5 + slot) * 64 + d0]      = v0[r];
      cumL[(rr * 5 + slot) * 64 + d0 + 16] = v1[r];
    }
  };
  if (kh == 0) {
    stor(0, s0a, s0b);
    stor(1, s1a, s1b);
    stor(2, s2a, s2b);
    stor(3, acc0, acc1);   // cumulative over k-tiles 0..15
  } else {
    stor(4, acc0, acc1);   // sum over k-tiles 16..32
  }
  __syncthreads();

  // ---- Phase 3: epilogue. wave w -> rows 4w..4w+3, lane = d ----
#pragma unroll
  for (int k4 = 0; k4 < 4; ++k4) {
    const int rl = w * 4 + k4;
    const size_t bt = (size_t)(row0 + rl);

    float q0 = cumL[(rl * 5 + 0) * 64 + lane];
    float q1 = cumL[(rl * 5 + 1) * 64 + lane];
    float q2 = cumL[(rl * 5 + 2) * 64 + lane];
    float q3 = cumL[(rl * 5 + 3) * 64 + lane] + cumL[(rl * 5 + 4) * 64 + lane];
    float b0 = q0, b1 = q1 - q0, b2 = q2 - q1, b3 = q3 - q2;

    float sv = fmaxf(stpacc[bt * Dn + lane], 0.f);
    float ssum = waveReduceSum(sv);
    float stp = sv / fmaxf(ssum * (1.0f / 64.0f), EPSF);

    float4 scv = *(const float4*)(scalar + bt * 4);
    float4 om  = *(const float4*)(obs_m  + bt * 4);
    float4 rm  = *(const float4*)(rel_m  + bt * 4);
    float obs_q = (om.x + om.y + om.z + om.w) * 0.25f;
    float rel_q = (rm.x + rm.y + rm.z + rm.w) * 0.25f;
    float is_snd = fminf(fmaxf(scv.x, 0.f), 1.f);
    float rho = fabsf(fminf(fmaxf(scv.y, -1.f), 1.f));

    float c0 = q3 * (1.0f / 1025.0f);
    float c1 = b0 * (1.0f / 22.0f);
    float c2 = b1 * (1.0f / 64.0f);
    float c3 = b2 * (1.0f / 256.0f);
    float c4 = b3 * (1.0f / 683.0f);

    float mean10 = (c0 + c1 + c2 + c3 + c4 + stp + obs_q + rel_q + is_snd + rho) * 0.1f;
    float logit = mean10 * (0.5f + 0.5f * is_snd);

    float2* op = (float2*)(out0 + (bt * Dn + lane) * 10);
    op[0] = make_float2(c0, c1);
    op[1] = make_float2(c2, c3);
    op[2] = make_float2(c4, stp);
    op[3] = make_float2(obs_q, rel_q);
    op[4] = make_float2(is_snd, rho);
    out1[bt * Dn + lane] = logit;
  }
}

extern "C" void kernel_launch(void* const* d_in, const int* in_sizes, int n_in,
                              void* d_out, int out_size, void* d_ws, size_t ws_size,
                              hipStream_t stream) {
  const float* phase   = (const float*)d_in[0];
  const float* comb    = (const float*)d_in[1];
  const float* scalar  = (const float*)d_in[2];
  const float* obs_m   = (const float*)d_in[3];
  const float* rel_m   = (const float*)d_in[4];
  const float* stpacc  = (const float*)d_in[5];
  const float* freq    = (const float*)d_in[6];
  const float* spacing = (const float*)d_in[7];

  float* out  = (float*)d_out;
  float* out0 = out;                                    // (B,T,D,10)
  float* out1 = out + (size_t)Bn * Tn * Dn * 10;        // (B,T,D)
  float* out2 = out1 + (size_t)Bn * Tn * Dn;            // (D,)
  float* out3 = out2 + Dn;                              // (D,)

  _Float16* basisT = (_Float16*)d_ws;                   // 64*KP fp16 = 135 KB

  prep_kernel<<<Dn, 256, 0, stream>>>(freq, spacing, basisT, out2, out3);
  fused_kernel<<<Bn * Tn / 16, 256, 0, stream>>>(
      phase, comb, basisT, scalar, obs_m, rel_m, stpacc, out0, out1);
}